// Round 7
// baseline (357.148 us; speedup 1.0000x reference)
//
#include <hip/hip_runtime.h>
#include <stdint.h>

#define NN 50000
#define NE 800000
#define NRP 50048      // padded rows (multiple of 64)
#define GG 782         // gemm grid: (NN + 63) / 64
#define NB 196         // hi buckets: ceil(NN / 256)
#define TT 2048        // edges per scatter block
#define SB 391         // scatter blocks: ceil(NE / TT)
#define SLAB 8192      // packA slab stride per bucket
#define SLABE (NRP * 32)   // ushort per 32-feature slab
#define SLABU (NRP * 16)   // uint32 per slab
#define SLABU2 (NRP * 8)   // uint2 per slab
#define AGGB 50000     // agg grid: 4 slabs x 12500 groups (4 nodes/group)

typedef __attribute__((ext_vector_type(8))) short bfx8;   // 8 bf16 (4 VGPRs)
typedef __attribute__((ext_vector_type(4))) float f32x4;  // MFMA acc

// ---- bf16 helpers (RNE) ----
__device__ inline unsigned short f2bf(float f) {
    union { float f; uint32_t u; } x; x.f = f;
    uint32_t u = x.u;
    return (unsigned short)((u + 0x7fffu + ((u >> 16) & 1u)) >> 16);
}
__device__ inline uint32_t pack2bf(float lo, float hi) {
    return (uint32_t)f2bf(lo) | ((uint32_t)f2bf(hi) << 16);
}
__device__ inline float bf2f(unsigned short h) {
    union { uint32_t u; float f; } c; c.u = ((uint32_t)h) << 16;
    return c.f;
}
__device__ inline float2 bfp2f2(uint32_t v) {
    union { uint32_t u; float f; } a, b;
    a.u = (v & 0xffffu) << 16;
    b.u = v & 0xffff0000u;
    return make_float2(a.f, b.f);
}
__device__ inline bfx8 ld8(const unsigned short* p) {
    union { uint4 u; bfx8 v; } c;
    c.u = *(const uint4*)p;
    return c.v;
}
__device__ inline bfx8 cvt8(float4 u, float4 v) {
    union { unsigned short s[8]; bfx8 r; } c;
    c.s[0] = f2bf(u.x); c.s[1] = f2bf(u.y); c.s[2] = f2bf(u.z); c.s[3] = f2bf(u.w);
    c.s[4] = f2bf(v.x); c.s[5] = f2bf(v.y); c.s[6] = f2bf(v.z); c.s[7] = f2bf(v.w);
    return c.r;
}

// ---------- D1: W transposes + zero bucket cursors ----------
__global__ void prep(const float* __restrict__ W1, const float* __restrict__ W2,
                     const float* __restrict__ W3,
                     unsigned short* __restrict__ WT1, unsigned short* __restrict__ WT2,
                     unsigned short* __restrict__ WT3, int* __restrict__ cursor) {
    if (blockIdx.x == 152) {
        if (threadIdx.x < NB) cursor[threadIdx.x] = 0;
        return;
    }
    int w = blockIdx.x * 256 + threadIdx.x;
    if (w < 16384) {
        int nn = w >> 7, k = w & 127;
        WT1[nn * 128 + k] = f2bf(W1[k * 128 + nn]);
    } else if (w < 32768) {
        int w2 = w - 16384, nn = w2 >> 7, k = w2 & 127;
        WT2[nn * 128 + k] = f2bf(W2[k * 128 + nn]);
    } else if (w < 38912) {
        int w2 = w - 32768, nn = w2 >> 7, k = w2 & 127;  // 48x128, zero-pad
        WT3[nn * 128 + k] = (nn < 40) ? f2bf(W3[k * 40 + nn]) : (unsigned short)0;
    }
}

// ---------- D2: layer-1 GEMM (slab-major out) ∪ bucket-scatter ----------
__global__ __launch_bounds__(256) void gemm1_hist(const float* __restrict__ X,
                                                  const unsigned short* __restrict__ WT,
                                                  unsigned short* __restrict__ G, int n,
                                                  const int* __restrict__ src,
                                                  const int* __restrict__ dst,
                                                  int* __restrict__ cursor,
                                                  uint32_t* __restrict__ packA, int e) {
    __shared__ int lc[NB];
    __shared__ int gb[NB];
    if (blockIdx.x >= GG) {
        int b = blockIdx.x - GG;
        int t = threadIdx.x;
        if (t < NB) lc[t] = 0;
        __syncthreads();
        int start = b * TT;
        int end = start + TT; if (end > e) end = e;
        int hi_[8], r_[8];
        uint32_t pk_[8];
#pragma unroll
        for (int j = 0; j < 8; j++) {
            int i = start + j * 256 + t;
            if (i < end) {
                int dd = dst[i], ss = src[i];
                hi_[j] = dd >> 8;
                pk_[j] = ((uint32_t)dd << 16) | (uint32_t)ss;
                r_[j] = atomicAdd(&lc[hi_[j]], 1);  // LDS rank
            } else r_[j] = -1;
        }
        __syncthreads();
        if (t < NB) {
            int c = lc[t];
            gb[t] = c ? atomicAdd(&cursor[t], c) : 0;  // global slab reservation
        }
        __syncthreads();
#pragma unroll
        for (int j = 0; j < 8; j++) {
            if (r_[j] >= 0)
                packA[(size_t)hi_[j] * SLAB + gb[hi_[j]] + r_[j]] = pk_[j];
        }
        return;
    }
    int wave = threadIdx.x >> 6;
    int lane = threadIdx.x & 63;
    int quad = lane >> 4;
    int c = lane & 15;
    int rowbase = blockIdx.x * 64 + wave * 16;

    int arow = rowbase + c;
    if (arow >= n) arow = n - 1;
    const float* ap = X + (size_t)arow * 128 + quad * 8;
    bfx8 a[4];
#pragma unroll
    for (int kc = 0; kc < 4; kc++) {
        float4 u = *(const float4*)(ap + kc * 32);
        float4 v = *(const float4*)(ap + kc * 32 + 4);
        a[kc] = cvt8(u, v);
    }

    f32x4 acc[8];
#pragma unroll
    for (int ct = 0; ct < 8; ct++) acc[ct] = (f32x4){0.f, 0.f, 0.f, 0.f};
#pragma unroll
    for (int ct = 0; ct < 8; ct++) {
        const unsigned short* bp = WT + (size_t)(ct * 16 + c) * 128 + quad * 8;
#pragma unroll
        for (int kc = 0; kc < 4; kc++) {
            bfx8 b = ld8(bp + kc * 32);
            acc[ct] = __builtin_amdgcn_mfma_f32_16x16x32_bf16(a[kc], b, acc[ct], 0, 0, 0);
        }
    }

    int r0 = rowbase + quad * 4;
    bool odd = lane & 1;
    uint32_t* Gu = (uint32_t*)G;
#pragma unroll
    for (int ct = 0; ct < 8; ct++) {
        float x0 = acc[ct][0], x1 = acc[ct][1], x2 = acc[ct][2], x3 = acc[ct][3];
        float y0 = __shfl_xor(x0, 1, 64), y1 = __shfl_xor(x1, 1, 64);
        float y2 = __shfl_xor(x2, 1, 64), y3 = __shfl_xor(x3, 1, 64);
        int colp = ct * 16 + (c & ~1);
        size_t sbase = (size_t)(colp >> 5) * SLABU + ((colp & 31) >> 1);
        if (!odd) {
            if (r0 + 0 < n) Gu[sbase + (size_t)(r0 + 0) * 16] = pack2bf(x0, y0);
            if (r0 + 1 < n) Gu[sbase + (size_t)(r0 + 1) * 16] = pack2bf(x1, y1);
        } else {
            if (r0 + 2 < n) Gu[sbase + (size_t)(r0 + 2) * 16] = pack2bf(y2, x2);
            if (r0 + 3 < n) Gu[sbase + (size_t)(r0 + 3) * 16] = pack2bf(y3, x3);
        }
    }
}

// ---------- D3: per-bucket fine sort -> row_ptr/deg/dinv + csr_src ----------
__global__ __launch_bounds__(256) void buildB(const uint32_t* __restrict__ packA,
                                              const int* __restrict__ cursor,
                                              int* __restrict__ row_ptr, int* __restrict__ deg,
                                              float* __restrict__ dinv,
                                              unsigned short* __restrict__ csr_src, int n) {
    __shared__ int s[256];
    __shared__ int cnt[256];
    __shared__ int rp[256];
    __shared__ int basehi, bcnt;
    int hi = blockIdx.x;
    int t = threadIdx.x;
    int bc = (t < NB) ? cursor[t] : 0;
    s[t] = bc;
    __syncthreads();
#pragma unroll
    for (int off = 1; off < 256; off <<= 1) {
        int y = (t >= off) ? s[t - off] : 0;
        __syncthreads();
        s[t] += y;
        __syncthreads();
    }
    if (t == hi) { basehi = s[t] - bc; bcnt = bc; }
    cnt[t] = 0;
    __syncthreads();
    int b0 = basehi;
    int mc = bcnt;
    const uint32_t* slab = packA + (size_t)hi * SLAB;
    for (int i = t; i < mc; i += 256)
        atomicAdd(&cnt[(slab[i] >> 16) & 0xFF], 1);  // LDS
    __syncthreads();
    int v = cnt[t];
    s[t] = v;
    __syncthreads();
#pragma unroll
    for (int off = 1; off < 256; off <<= 1) {
        int y = (t >= off) ? s[t - off] : 0;
        __syncthreads();
        s[t] += y;
        __syncthreads();
    }
    rp[t] = b0 + s[t] - v;  // absolute row start for node hi*256+t
    int node = hi * 256 + t;
    if (node < n) {
        row_ptr[node] = rp[t];
        deg[node] = v;
        dinv[node] = rsqrtf(1.0f + (float)v);
    }
    cnt[t] = 0;
    __syncthreads();
    for (int i = t; i < mc; i += 256) {
        uint32_t p = slab[i];
        int lo = (p >> 16) & 0xFF;
        int r = atomicAdd(&cnt[lo], 1);  // LDS
        csr_src[rp[lo] + r] = (unsigned short)(p & 0xFFFF);
    }
}

// ---------- layer-2 GEMM: slab-major A in, slab-major (dinv-scaled) out ----------
__global__ __launch_bounds__(256) void gemm128_mfma(const unsigned short* __restrict__ A,
                                                    const unsigned short* __restrict__ WT,
                                                    const float* __restrict__ dinv,
                                                    unsigned short* __restrict__ G, int n) {
    int wave = threadIdx.x >> 6;
    int lane = threadIdx.x & 63;
    int quad = lane >> 4;
    int c = lane & 15;
    int rowbase = blockIdx.x * 64 + wave * 16;

    int arow = rowbase + c;
    if (arow >= n) arow = n - 1;
    const unsigned short* ap = A + (size_t)arow * 32 + quad * 8;  // slab-major
    bfx8 a[4];
#pragma unroll
    for (int kc = 0; kc < 4; kc++) a[kc] = ld8(ap + (size_t)kc * SLABE);

    f32x4 acc[8];
#pragma unroll
    for (int ct = 0; ct < 8; ct++) acc[ct] = (f32x4){0.f, 0.f, 0.f, 0.f};
#pragma unroll
    for (int ct = 0; ct < 8; ct++) {
        const unsigned short* bp = WT + (size_t)(ct * 16 + c) * 128 + quad * 8;
#pragma unroll
        for (int kc = 0; kc < 4; kc++) {
            bfx8 b = ld8(bp + kc * 32);
            acc[ct] = __builtin_amdgcn_mfma_f32_16x16x32_bf16(a[kc], b, acc[ct], 0, 0, 0);
        }
    }

    int r0 = rowbase + quad * 4;
    float di[4];
#pragma unroll
    for (int r = 0; r < 4; r++) {
        int rr = r0 + r;
        di[r] = dinv[rr < n ? rr : 0];
    }
    bool odd = lane & 1;
    uint32_t* Gu = (uint32_t*)G;
#pragma unroll
    for (int ct = 0; ct < 8; ct++) {
        float x0 = acc[ct][0], x1 = acc[ct][1], x2 = acc[ct][2], x3 = acc[ct][3];
        float y0 = __shfl_xor(x0, 1, 64), y1 = __shfl_xor(x1, 1, 64);
        float y2 = __shfl_xor(x2, 1, 64), y3 = __shfl_xor(x3, 1, 64);
        int colp = ct * 16 + (c & ~1);
        size_t sbase = (size_t)(colp >> 5) * SLABU + ((colp & 31) >> 1);
        if (!odd) {
            if (r0 + 0 < n) Gu[sbase + (size_t)(r0 + 0) * 16] = pack2bf(di[0] * x0, di[0] * y0);
            if (r0 + 1 < n) Gu[sbase + (size_t)(r0 + 1) * 16] = pack2bf(di[1] * x1, di[1] * y1);
        } else {
            if (r0 + 2 < n) Gu[sbase + (size_t)(r0 + 2) * 16] = pack2bf(di[2] * y2, di[2] * x2);
            if (r0 + 3 < n) Gu[sbase + (size_t)(r0 + 3) * 16] = pack2bf(di[3] * y3, di[3] * x3);
        }
    }
}

// ---------- layer-3 GEMM: slab-major A in, LINEAR 40-wide out ----------
__global__ __launch_bounds__(256) void gemm40_mfma(const unsigned short* __restrict__ A,
                                                   const unsigned short* __restrict__ WT,
                                                   const float* __restrict__ dinv,
                                                   unsigned short* __restrict__ G, int n) {
    int wave = threadIdx.x >> 6;
    int lane = threadIdx.x & 63;
    int quad = lane >> 4;
    int c = lane & 15;
    int rowbase = blockIdx.x * 64 + wave * 16;

    int arow = rowbase + c;
    if (arow >= n) arow = n - 1;
    const unsigned short* ap = A + (size_t)arow * 32 + quad * 8;  // slab-major
    bfx8 a[4];
#pragma unroll
    for (int kc = 0; kc < 4; kc++) a[kc] = ld8(ap + (size_t)kc * SLABE);

    f32x4 acc[3];
#pragma unroll
    for (int ct = 0; ct < 3; ct++) acc[ct] = (f32x4){0.f, 0.f, 0.f, 0.f};
#pragma unroll
    for (int ct = 0; ct < 3; ct++) {
        const unsigned short* bp = WT + (size_t)(ct * 16 + c) * 128 + quad * 8;
#pragma unroll
        for (int kc = 0; kc < 4; kc++) {
            bfx8 b = ld8(bp + kc * 32);
            acc[ct] = __builtin_amdgcn_mfma_f32_16x16x32_bf16(a[kc], b, acc[ct], 0, 0, 0);
        }
    }

    int r0 = rowbase + quad * 4;
    float di[4];
#pragma unroll
    for (int r = 0; r < 4; r++) {
        int rr = r0 + r;
        di[r] = dinv[rr < n ? rr : 0];
    }
    bool odd = lane & 1;
#pragma unroll
    for (int ct = 0; ct < 3; ct++) {
        float x0 = acc[ct][0], x1 = acc[ct][1], x2 = acc[ct][2], x3 = acc[ct][3];
        float y0 = __shfl_xor(x0, 1, 64), y1 = __shfl_xor(x1, 1, 64);
        float y2 = __shfl_xor(x2, 1, 64), y3 = __shfl_xor(x3, 1, 64);
        int colp = ct * 16 + (c & ~1);
        if (colp >= 40) continue;
        if (!odd) {
            if (r0 + 0 < n) *(uint32_t*)(&G[(size_t)(r0 + 0) * 40 + colp]) = pack2bf(di[0] * x0, di[0] * y0);
            if (r0 + 1 < n) *(uint32_t*)(&G[(size_t)(r0 + 1) * 40 + colp]) = pack2bf(di[1] * x1, di[1] * y1);
        } else {
            if (r0 + 2 < n) *(uint32_t*)(&G[(size_t)(r0 + 2) * 40 + colp]) = pack2bf(di[2] * y2, di[2] * x2);
            if (r0 + 3 < n) *(uint32_t*)(&G[(size_t)(r0 + 3) * 40 + colp]) = pack2bf(di[3] * y3, di[3] * x3);
        }
    }
}

// ---------- D4: layer-1 aggregate, slab-sliced, 8 edges/instruction ----------
// R7: R4's slab locality (FETCH 25.6MB verified) + wide instruction economy.
// Slab row = 32 feats = 64B = 8 lanes x uint2; one 64-lane gather covers 8
// edges. Wave = node x slab; slab = (bid&7)>>1 pins each slab to 2 XCDs.
// Grid = 50000: grp in [0,12500), 4 nodes/block (R6 crash: 100000 -> OOB).
__global__ __launch_bounds__(256) void agg128_l1(const unsigned short* __restrict__ G,
                                                 const int* __restrict__ row_ptr,
                                                 const int* __restrict__ deg,
                                                 const unsigned short* __restrict__ csr_src,
                                                 const float* __restrict__ dinv,
                                                 const float* __restrict__ b,
                                                 unsigned short* __restrict__ Y, int n) {
    int bi = blockIdx.x;
    int xs = bi & 7;
    int slab = xs >> 1;
    int grp = (bi >> 3) * 2 + (xs & 1);      // [0, 12500)
    int node = grp * 4 + (threadIdx.x >> 6);
    if (node >= n) return;
    int l = threadIdx.x & 63;
    int slot = l >> 3, f = l & 7;
    const uint2* Gs = (const uint2*)G + (size_t)slab * SLABU2;

    float dn = dinv[node];
    float4 acc = make_float4(0.f, 0.f, 0.f, 0.f);
    int p = row_ptr[node];
    int p1 = p + deg[node];
    for (int q = p; q < p1; q += 8) {
        int i = q + slot;
        bool v = i < p1;
        int s = csr_src[v ? i : p];
        float d = v ? dinv[s] : 0.f;
        uint2 r = Gs[(size_t)s * 8 + f];
        float2 lo = bfp2f2(r.x), hi = bfp2f2(r.y);
        acc.x = fmaf(d, lo.x, acc.x);
        acc.y = fmaf(d, lo.y, acc.y);
        acc.z = fmaf(d, hi.x, acc.z);
        acc.w = fmaf(d, hi.y, acc.w);
    }
#pragma unroll
    for (int off = 8; off < 64; off <<= 1) {
        acc.x += __shfl_xor(acc.x, off, 64);
        acc.y += __shfl_xor(acc.y, off, 64);
        acc.z += __shfl_xor(acc.z, off, 64);
        acc.w += __shfl_xor(acc.w, off, 64);
    }
    // self term (unscaled H1): acc += dn * self
    uint2 sr = Gs[(size_t)node * 8 + f];
    float2 slo = bfp2f2(sr.x), shi = bfp2f2(sr.y);
    acc.x = fmaf(dn, slo.x, acc.x);
    acc.y = fmaf(dn, slo.y, acc.y);
    acc.z = fmaf(dn, shi.x, acc.z);
    acc.w = fmaf(dn, shi.y, acc.w);
    float4 bb = ((const float4*)b)[slab * 8 + f];
    float r0 = fmaf(dn, acc.x, bb.x);
    float r1 = fmaf(dn, acc.y, bb.y);
    float r2 = fmaf(dn, acc.z, bb.z);
    float r3 = fmaf(dn, acc.w, bb.w);
    if (slot == 0) {
        uint2 o;
        o.x = pack2bf(r0 > 0.f ? r0 : 0.f, r1 > 0.f ? r1 : 0.f);
        o.y = pack2bf(r2 > 0.f ? r2 : 0.f, r3 > 0.f ? r3 : 0.f);
        ((uint2*)Y)[(size_t)slab * SLABU2 + (size_t)node * 8 + f] = o;
    }
}

// ---------- D6: layer-2 aggregate, slab-sliced (G pre-scaled) ----------
__global__ __launch_bounds__(256) void agg128(const unsigned short* __restrict__ G,
                                              const int* __restrict__ row_ptr,
                                              const int* __restrict__ deg,
                                              const unsigned short* __restrict__ csr_src,
                                              const float* __restrict__ dinv,
                                              const float* __restrict__ b,
                                              unsigned short* __restrict__ Y, int n) {
    int bi = blockIdx.x;
    int xs = bi & 7;
    int slab = xs >> 1;
    int grp = (bi >> 3) * 2 + (xs & 1);
    int node = grp * 4 + (threadIdx.x >> 6);
    if (node >= n) return;
    int l = threadIdx.x & 63;
    int slot = l >> 3, f = l & 7;
    const uint2* Gs = (const uint2*)G + (size_t)slab * SLABU2;

    float4 acc = make_float4(0.f, 0.f, 0.f, 0.f);
    int p = row_ptr[node];
    int p1 = p + deg[node];
    for (int q = p; q < p1; q += 8) {
        int i = q + slot;
        bool v = i < p1;
        int s = csr_src[v ? i : p];
        float d = v ? 1.f : 0.f;
        uint2 r = Gs[(size_t)s * 8 + f];
        float2 lo = bfp2f2(r.x), hi = bfp2f2(r.y);
        acc.x = fmaf(d, lo.x, acc.x);
        acc.y = fmaf(d, lo.y, acc.y);
        acc.z = fmaf(d, hi.x, acc.z);
        acc.w = fmaf(d, hi.y, acc.w);
    }
#pragma unroll
    for (int off = 8; off < 64; off <<= 1) {
        acc.x += __shfl_xor(acc.x, off, 64);
        acc.y += __shfl_xor(acc.y, off, 64);
        acc.z += __shfl_xor(acc.z, off, 64);
        acc.w += __shfl_xor(acc.w, off, 64);
    }
    // self (pre-scaled)
    uint2 sr = Gs[(size_t)node * 8 + f];
    float2 slo = bfp2f2(sr.x), shi = bfp2f2(sr.y);
    acc.x += slo.x; acc.y += slo.y; acc.z += shi.x; acc.w += shi.y;
    float dn = dinv[node];
    float4 bb = ((const float4*)b)[slab * 8 + f];
    float r0 = fmaf(dn, acc.x, bb.x);
    float r1 = fmaf(dn, acc.y, bb.y);
    float r2 = fmaf(dn, acc.z, bb.z);
    float r3 = fmaf(dn, acc.w, bb.w);
    if (slot == 0) {
        uint2 o;
        o.x = pack2bf(r0 > 0.f ? r0 : 0.f, r1 > 0.f ? r1 : 0.f);
        o.y = pack2bf(r2 > 0.f ? r2 : 0.f, r3 > 0.f ? r3 : 0.f);
        ((uint2*)Y)[(size_t)slab * SLABU2 + (size_t)node * 8 + f] = o;
    }
}

// ---------- D8: 40-wide aggregate + log_softmax, uint2 gather ----------
__global__ __launch_bounds__(256) void agg40_lsm(const unsigned short* __restrict__ G,
                                                 const int* __restrict__ row_ptr,
                                                 const int* __restrict__ deg,
                                                 const unsigned short* __restrict__ csr_src,
                                                 const float* __restrict__ dinv,
                                                 const float* __restrict__ b,
                                                 float* __restrict__ Y, int n) {
    int node = blockIdx.x * 4 + (threadIdx.x >> 6);
    if (node >= n) return;
    int l = threadIdx.x & 63;
    int h = l >> 5, fl = l & 31;
    bool act = fl < 10;
    int flc = act ? fl : 0;
    const uint2* Gr = (const uint2*)G;  // row = 10 uint2 (80B)

    float4 acc = make_float4(0.f, 0.f, 0.f, 0.f);
    if (h == 0) {
        uint2 sq = Gr[(size_t)node * 10 + flc];
        float2 a0 = bfp2f2(sq.x), a1 = bfp2f2(sq.y);
        acc = make_float4(a0.x, a0.y, a1.x, a1.y);  // self (pre-scaled)
    }
    int p = row_ptr[node];
    int p1 = p + deg[node];
    for (int q = p; q < p1; q += 8) {
        int i0 = q + h, i1 = q + 2 + h, i2 = q + 4 + h, i3 = q + 6 + h;
        bool v0 = i0 < p1, v1 = i1 < p1, v2 = i2 < p1, v3 = i3 < p1;
        int s0 = csr_src[v0 ? i0 : p], s1 = csr_src[v1 ? i1 : p];
        int s2 = csr_src[v2 ? i2 : p], s3 = csr_src[v3 ? i3 : p];
        float d0 = v0 ? 1.f : 0.f, d1 = v1 ? 1.f : 0.f;
        float d2 = v2 ? 1.f : 0.f, d3 = v3 ? 1.f : 0.f;
        uint2 q0 = Gr[(size_t)s0 * 10 + flc], q1 = Gr[(size_t)s1 * 10 + flc];
        uint2 q2 = Gr[(size_t)s2 * 10 + flc], q3 = Gr[(size_t)s3 * 10 + flc];
        float2 x0 = bfp2f2(q0.x), y0 = bfp2f2(q0.y);
        float2 x1 = bfp2f2(q1.x), y1 = bfp2f2(q1.y);
        float2 x2 = bfp2f2(q2.x), y2 = bfp2f2(q2.y);
        float2 x3 = bfp2f2(q3.x), y3 = bfp2f2(q3.y);
        acc.x += fmaf(d0, x0.x, d1 * x1.x) + fmaf(d2, x2.x, d3 * x3.x);
        acc.y += fmaf(d0, x0.y, d1 * x1.y) + fmaf(d2, x2.y, d3 * x3.y);
        acc.z += fmaf(d0, y0.x, d1 * y1.x) + fmaf(d2, y2.x, d3 * y3.x);
        acc.w += fmaf(d0, y0.y, d1 * y1.y) + fmaf(d2, y2.y, d3 * y3.y);
    }
    acc.x += __shfl_xor(acc.x, 32, 64);
    acc.y += __shfl_xor(acc.y, 32, 64);
    acc.z += __shfl_xor(acc.z, 32, 64);
    acc.w += __shfl_xor(acc.w, 32, 64);
    float dn = dinv[node];
    const float4* b4 = (const float4*)b;  // 40 floats = 10 float4
    float4 bb = b4[flc];
    float v0_ = fmaf(dn, acc.x, bb.x);
    float v1_ = fmaf(dn, acc.y, bb.y);
    float v2_ = fmaf(dn, acc.z, bb.z);
    float v3_ = fmaf(dn, acc.w, bb.w);
    float m = act ? fmaxf(fmaxf(v0_, v1_), fmaxf(v2_, v3_)) : -1e30f;
#pragma unroll
    for (int off = 8; off > 0; off >>= 1) m = fmaxf(m, __shfl_xor(m, off, 16));
    float e0 = act ? expf(v0_ - m) : 0.f;
    float e1 = act ? expf(v1_ - m) : 0.f;
    float e2 = act ? expf(v2_ - m) : 0.f;
    float e3 = act ? expf(v3_ - m) : 0.f;
    float s_ = ((e0 + e1) + (e2 + e3));
#pragma unroll
    for (int off = 8; off > 0; off >>= 1) s_ += __shfl_xor(s_, off, 16);
    float ls = logf(s_) + m;
    if (h == 0 && act) {
        float4 o = make_float4(v0_ - ls, v1_ - ls, v2_ - ls, v3_ - ls);
        ((float4*)Y)[(size_t)node * 10 + fl] = o;
    }
}

// ---------- launch ----------

extern "C" void kernel_launch(void* const* d_in, const int* in_sizes, int n_in,
                              void* d_out, int out_size, void* d_ws, size_t ws_size,
                              hipStream_t stream) {
    const float* x  = (const float*)d_in[0];
    const int*   ei = (const int*)d_in[1];
    const float* W1 = (const float*)d_in[2];
    const float* b1 = (const float*)d_in[3];
    const float* W2 = (const float*)d_in[4];
    const float* b2 = (const float*)d_in[5];
    const float* W3 = (const float*)d_in[6];
    const float* b3 = (const float*)d_in[7];
    float* out = (float*)d_out;

    const int n = NN, e = NE;
    const int* srcI = ei;
    const int* dstI = ei + e;

    char* ws = (char*)d_ws;
    int*            deg     = (int*)ws;                          // n ints
    int*            row_ptr = (int*)(ws + 200704);               // n ints
    float*          dinv    = (float*)(ws + 401408);             // n fp32
    int*            cursor  = (int*)(ws + 602112);               // NB ints
    uint32_t*       packA   = (uint32_t*)(ws + 603136);          // NB*SLAB uint32 (6.4MB)
    unsigned short* csr_src = (unsigned short*)(ws + 7025664);   // E ushort (1.6MB)
    unsigned short* WT1     = (unsigned short*)(ws + 8625664);   // 128x128 bf16
    unsigned short* WT2     = (unsigned short*)(ws + 8658432);
    unsigned short* WT3     = (unsigned short*)(ws + 8691200);   // 48x128 bf16
    unsigned short* bufG    = (unsigned short*)(ws + 8703488);   // 4 slabs x NRP x 32 (12.8MB)
    unsigned short* bufA    = (unsigned short*)(ws + 21515776);  // 4 slabs x NRP x 32 (12.8MB)

    // D1: W transposes + zero cursors
    prep<<<153, 256, 0, stream>>>(W1, W2, W3, WT1, WT2, WT3, cursor);
    // D2: layer-1 GEMM (slab-major out) ∪ slab scatter
    gemm1_hist<<<GG + SB, 256, 0, stream>>>(x, WT1, bufG, n, srcI, dstI, cursor, packA, e);
    // D3: per-bucket sort -> CSR + row_ptr/deg/dinv
    buildB<<<NB, 256, 0, stream>>>(packA, cursor, row_ptr, deg, dinv, csr_src, n);
    // D4: aggregate layer 1 (slab-sliced, 8 edges/instr, per-edge dinv)
    agg128_l1<<<AGGB, 256, 0, stream>>>(bufG, row_ptr, deg, csr_src, dinv, b1, bufA, n);
    // D5: layer-2 GEMM (slab in/out, pre-scaled)
    gemm128_mfma<<<GG, 256, 0, stream>>>(bufA, WT2, dinv, bufG, n);
    // D6: aggregate layer 2 (slab-sliced)
    agg128<<<AGGB, 256, 0, stream>>>(bufG, row_ptr, deg, csr_src, dinv, b2, bufA, n);
    // D7: layer-3 GEMM (slab in, linear 40-wide out)
    gemm40_mfma<<<GG, 256, 0, stream>>>(bufA, WT3, dinv, bufG, n);
    // D8: aggregate + log_softmax -> out
    agg40_lsm<<<(n + 3) / 4, 256, 0, stream>>>(bufG, row_ptr, deg, csr_src, dinv, b3, out, n);
}

// Round 8
// 279.423 us; speedup vs baseline: 1.2782x; 1.2782x over previous
//
#include <hip/hip_runtime.h>
#include <stdint.h>

#define NN 50000
#define NE 800000
#define GG 782     // gemm grid: (NN + 63) / 64
#define NB 196     // hi buckets: ceil(NN / 256)
#define TT 2048    // edges per scatter block
#define SB 391     // scatter blocks: ceil(NE / TT)
#define SLAB 8192  // packA slab stride per bucket

typedef __attribute__((ext_vector_type(8))) short bfx8;   // 8 bf16 (4 VGPRs)
typedef __attribute__((ext_vector_type(4))) float f32x4;  // MFMA acc

// ---- bf16 helpers (RNE) ----
__device__ inline unsigned short f2bf(float f) {
    union { float f; uint32_t u; } x; x.f = f;
    uint32_t u = x.u;
    return (unsigned short)((u + 0x7fffu + ((u >> 16) & 1u)) >> 16);
}
__device__ inline uint32_t pack2bf(float lo, float hi) {
    return (uint32_t)f2bf(lo) | ((uint32_t)f2bf(hi) << 16);
}
__device__ inline float bf2f(unsigned short h) {
    union { uint32_t u; float f; } c; c.u = ((uint32_t)h) << 16;
    return c.f;
}
__device__ inline float2 bfp2f2(uint32_t v) {
    union { uint32_t u; float f; } a, b;
    a.u = (v & 0xffffu) << 16;
    b.u = v & 0xffff0000u;
    return make_float2(a.f, b.f);
}
__device__ inline bfx8 ld8(const unsigned short* p) {
    union { uint4 u; bfx8 v; } c;
    c.u = *(const uint4*)p;
    return c.v;
}
__device__ inline bfx8 cvt8(float4 u, float4 v) {
    union { unsigned short s[8]; bfx8 r; } c;
    c.s[0] = f2bf(u.x); c.s[1] = f2bf(u.y); c.s[2] = f2bf(u.z); c.s[3] = f2bf(u.w);
    c.s[4] = f2bf(v.x); c.s[5] = f2bf(v.y); c.s[6] = f2bf(v.z); c.s[7] = f2bf(v.w);
    return c.r;
}

// ---------- D1: W transposes + zero bucket cursors ----------
__global__ void prep(const float* __restrict__ W1, const float* __restrict__ W2,
                     const float* __restrict__ W3,
                     unsigned short* __restrict__ WT1, unsigned short* __restrict__ WT2,
                     unsigned short* __restrict__ WT3, int* __restrict__ cursor) {
    if (blockIdx.x == 152) {
        if (threadIdx.x < NB) cursor[threadIdx.x] = 0;
        return;
    }
    int w = blockIdx.x * 256 + threadIdx.x;
    if (w < 16384) {
        int nn = w >> 7, k = w & 127;
        WT1[nn * 128 + k] = f2bf(W1[k * 128 + nn]);
    } else if (w < 32768) {
        int w2 = w - 16384, nn = w2 >> 7, k = w2 & 127;
        WT2[nn * 128 + k] = f2bf(W2[k * 128 + nn]);
    } else if (w < 38912) {
        int w2 = w - 32768, nn = w2 >> 7, k = w2 & 127;  // 48x128, zero-pad
        WT3[nn * 128 + k] = (nn < 40) ? f2bf(W3[k * 40 + nn]) : (unsigned short)0;
    }
}

// ---------- D2: layer-1 GEMM (linear G, UNSCALED) ∪ bucket-scatter ----------
__global__ __launch_bounds__(256) void gemm1_hist(const float* __restrict__ X,
                                                  const unsigned short* __restrict__ WT,
                                                  unsigned short* __restrict__ G, int n,
                                                  const int* __restrict__ src,
                                                  const int* __restrict__ dst,
                                                  int* __restrict__ cursor,
                                                  uint32_t* __restrict__ packA, int e) {
    __shared__ int lc[NB];
    __shared__ int gb[NB];
    if (blockIdx.x >= GG) {
        int b = blockIdx.x - GG;
        int t = threadIdx.x;
        if (t < NB) lc[t] = 0;
        __syncthreads();
        int start = b * TT;
        int end = start + TT; if (end > e) end = e;
        int hi_[8], r_[8];
        uint32_t pk_[8];
#pragma unroll
        for (int j = 0; j < 8; j++) {
            int i = start + j * 256 + t;
            if (i < end) {
                int dd = dst[i], ss = src[i];
                hi_[j] = dd >> 8;
                pk_[j] = ((uint32_t)dd << 16) | (uint32_t)ss;
                r_[j] = atomicAdd(&lc[hi_[j]], 1);  // LDS rank
            } else r_[j] = -1;
        }
        __syncthreads();
        if (t < NB) {
            int c = lc[t];
            gb[t] = c ? atomicAdd(&cursor[t], c) : 0;  // global slab reservation
        }
        __syncthreads();
#pragma unroll
        for (int j = 0; j < 8; j++) {
            if (r_[j] >= 0)
                packA[(size_t)hi_[j] * SLAB + gb[hi_[j]] + r_[j]] = pk_[j];
        }
        return;
    }
    int wave = threadIdx.x >> 6;
    int lane = threadIdx.x & 63;
    int quad = lane >> 4;
    int c = lane & 15;
    int rowbase = blockIdx.x * 64 + wave * 16;

    int arow = rowbase + c;
    if (arow >= n) arow = n - 1;
    const float* ap = X + (size_t)arow * 128 + quad * 8;
    bfx8 a[4];
#pragma unroll
    for (int kc = 0; kc < 4; kc++) {
        float4 u = *(const float4*)(ap + kc * 32);
        float4 v = *(const float4*)(ap + kc * 32 + 4);
        a[kc] = cvt8(u, v);
    }

    f32x4 acc[8];
#pragma unroll
    for (int ct = 0; ct < 8; ct++) acc[ct] = (f32x4){0.f, 0.f, 0.f, 0.f};
#pragma unroll
    for (int ct = 0; ct < 8; ct++) {
        const unsigned short* bp = WT + (size_t)(ct * 16 + c) * 128 + quad * 8;
#pragma unroll
        for (int kc = 0; kc < 4; kc++) {
            bfx8 b = ld8(bp + kc * 32);
            acc[ct] = __builtin_amdgcn_mfma_f32_16x16x32_bf16(a[kc], b, acc[ct], 0, 0, 0);
        }
    }

    int r0 = rowbase + quad * 4;
    bool odd = lane & 1;
#pragma unroll
    for (int ct = 0; ct < 8; ct++) {
        float x0 = acc[ct][0], x1 = acc[ct][1], x2 = acc[ct][2], x3 = acc[ct][3];
        float y0 = __shfl_xor(x0, 1, 64), y1 = __shfl_xor(x1, 1, 64);
        float y2 = __shfl_xor(x2, 1, 64), y3 = __shfl_xor(x3, 1, 64);
        int colp = ct * 16 + (c & ~1);
        if (!odd) {
            if (r0 + 0 < n) *(uint32_t*)(&G[(size_t)(r0 + 0) * 128 + colp]) = pack2bf(x0, y0);
            if (r0 + 1 < n) *(uint32_t*)(&G[(size_t)(r0 + 1) * 128 + colp]) = pack2bf(x1, y1);
        } else {
            if (r0 + 2 < n) *(uint32_t*)(&G[(size_t)(r0 + 2) * 128 + colp]) = pack2bf(y2, x2);
            if (r0 + 3 < n) *(uint32_t*)(&G[(size_t)(r0 + 3) * 128 + colp]) = pack2bf(y3, x3);
        }
    }
}

// ---------- D3: per-bucket sort -> row_ptr/deg/dinv + csr_src + H1 pre-scale ----------
// R8: epilogue scales this bucket's 256 G rows by dinv (coalesced 64KB RMW),
// so layer-1 aggregate needs NO per-edge dinv gather (same form as layer 2).
__global__ __launch_bounds__(256) void buildB(const uint32_t* __restrict__ packA,
                                              const int* __restrict__ cursor,
                                              int* __restrict__ row_ptr, int* __restrict__ deg,
                                              float* __restrict__ dinv,
                                              unsigned short* __restrict__ csr_src,
                                              unsigned short* __restrict__ G, int n) {
    __shared__ int s[256];
    __shared__ int cnt[256];
    __shared__ int rp[256];
    __shared__ float sdinv[256];
    __shared__ int basehi, bcnt;
    int hi = blockIdx.x;
    int t = threadIdx.x;
    int bc = (t < NB) ? cursor[t] : 0;
    s[t] = bc;
    __syncthreads();
#pragma unroll
    for (int off = 1; off < 256; off <<= 1) {
        int y = (t >= off) ? s[t - off] : 0;
        __syncthreads();
        s[t] += y;
        __syncthreads();
    }
    if (t == hi) { basehi = s[t] - bc; bcnt = bc; }
    cnt[t] = 0;
    __syncthreads();
    int b0 = basehi;
    int mc = bcnt;
    const uint32_t* slab = packA + (size_t)hi * SLAB;
    for (int i = t; i < mc; i += 256)
        atomicAdd(&cnt[(slab[i] >> 16) & 0xFF], 1);  // LDS
    __syncthreads();
    int v = cnt[t];
    s[t] = v;
    __syncthreads();
#pragma unroll
    for (int off = 1; off < 256; off <<= 1) {
        int y = (t >= off) ? s[t - off] : 0;
        __syncthreads();
        s[t] += y;
        __syncthreads();
    }
    rp[t] = b0 + s[t] - v;  // absolute row start for node hi*256+t
    float dv = rsqrtf(1.0f + (float)v);
    sdinv[t] = dv;
    int node = hi * 256 + t;
    if (node < n) {
        row_ptr[node] = rp[t];
        deg[node] = v;
        dinv[node] = dv;
    }
    cnt[t] = 0;
    __syncthreads();
    for (int i = t; i < mc; i += 256) {
        uint32_t p = slab[i];
        int lo = (p >> 16) & 0xFF;
        int r = atomicAdd(&cnt[lo], 1);  // LDS
        csr_src[rp[lo] + r] = (unsigned short)(p & 0xFFFF);
    }
    // H1 pre-scale: G'[node] = dinv[node] * H1[node] for this bucket's rows
    int nbase = hi * 256;
    int nvalid = n - nbase; if (nvalid > 256) nvalid = 256;
    uint2* Gb = (uint2*)G + (size_t)nbase * 32;
#pragma unroll 4
    for (int k = 0; k < 32; k++) {
        int idx = k * 256 + t;
        int no = idx >> 5;
        if (no < nvalid) {
            uint2 vv = Gb[idx];
            float dd = sdinv[no];
            float2 x = bfp2f2(vv.x), y = bfp2f2(vv.y);
            uint2 o;
            o.x = pack2bf(dd * x.x, dd * x.y);
            o.y = pack2bf(dd * y.x, dd * y.y);
            Gb[idx] = o;
        }
    }
}

// ---------- GEMMs for layers 2/3: pre-scale rows by dinv (epilogue) ----------
__global__ __launch_bounds__(256) void gemm128_mfma(const unsigned short* __restrict__ A,
                                                    const unsigned short* __restrict__ WT,
                                                    const float* __restrict__ dinv,
                                                    unsigned short* __restrict__ G, int n) {
    int wave = threadIdx.x >> 6;
    int lane = threadIdx.x & 63;
    int quad = lane >> 4;
    int c = lane & 15;
    int rowbase = blockIdx.x * 64 + wave * 16;

    int arow = rowbase + c;
    if (arow >= n) arow = n - 1;
    const unsigned short* ap = A + (size_t)arow * 128 + quad * 8;
    bfx8 a[4];
#pragma unroll
    for (int kc = 0; kc < 4; kc++) a[kc] = ld8(ap + kc * 32);

    f32x4 acc[8];
#pragma unroll
    for (int ct = 0; ct < 8; ct++) acc[ct] = (f32x4){0.f, 0.f, 0.f, 0.f};
#pragma unroll
    for (int ct = 0; ct < 8; ct++) {
        const unsigned short* bp = WT + (size_t)(ct * 16 + c) * 128 + quad * 8;
#pragma unroll
        for (int kc = 0; kc < 4; kc++) {
            bfx8 b = ld8(bp + kc * 32);
            acc[ct] = __builtin_amdgcn_mfma_f32_16x16x32_bf16(a[kc], b, acc[ct], 0, 0, 0);
        }
    }

    int r0 = rowbase + quad * 4;
    float di[4];
#pragma unroll
    for (int r = 0; r < 4; r++) {
        int rr = r0 + r;
        di[r] = dinv[rr < n ? rr : 0];
    }
    bool odd = lane & 1;
#pragma unroll
    for (int ct = 0; ct < 8; ct++) {
        float x0 = acc[ct][0], x1 = acc[ct][1], x2 = acc[ct][2], x3 = acc[ct][3];
        float y0 = __shfl_xor(x0, 1, 64), y1 = __shfl_xor(x1, 1, 64);
        float y2 = __shfl_xor(x2, 1, 64), y3 = __shfl_xor(x3, 1, 64);
        int colp = ct * 16 + (c & ~1);
        if (!odd) {
            if (r0 + 0 < n) *(uint32_t*)(&G[(size_t)(r0 + 0) * 128 + colp]) = pack2bf(di[0] * x0, di[0] * y0);
            if (r0 + 1 < n) *(uint32_t*)(&G[(size_t)(r0 + 1) * 128 + colp]) = pack2bf(di[1] * x1, di[1] * y1);
        } else {
            if (r0 + 2 < n) *(uint32_t*)(&G[(size_t)(r0 + 2) * 128 + colp]) = pack2bf(di[2] * y2, di[2] * x2);
            if (r0 + 3 < n) *(uint32_t*)(&G[(size_t)(r0 + 3) * 128 + colp]) = pack2bf(di[3] * y3, di[3] * x3);
        }
    }
}

__global__ __launch_bounds__(256) void gemm40_mfma(const unsigned short* __restrict__ A,
                                                   const unsigned short* __restrict__ WT,
                                                   const float* __restrict__ dinv,
                                                   unsigned short* __restrict__ G, int n) {
    int wave = threadIdx.x >> 6;
    int lane = threadIdx.x & 63;
    int quad = lane >> 4;
    int c = lane & 15;
    int rowbase = blockIdx.x * 64 + wave * 16;

    int arow = rowbase + c;
    if (arow >= n) arow = n - 1;
    const unsigned short* ap = A + (size_t)arow * 128 + quad * 8;
    bfx8 a[4];
#pragma unroll
    for (int kc = 0; kc < 4; kc++) a[kc] = ld8(ap + kc * 32);

    f32x4 acc[3];
#pragma unroll
    for (int ct = 0; ct < 3; ct++) acc[ct] = (f32x4){0.f, 0.f, 0.f, 0.f};
#pragma unroll
    for (int ct = 0; ct < 3; ct++) {
        const unsigned short* bp = WT + (size_t)(ct * 16 + c) * 128 + quad * 8;
#pragma unroll
        for (int kc = 0; kc < 4; kc++) {
            bfx8 b = ld8(bp + kc * 32);
            acc[ct] = __builtin_amdgcn_mfma_f32_16x16x32_bf16(a[kc], b, acc[ct], 0, 0, 0);
        }
    }

    int r0 = rowbase + quad * 4;
    float di[4];
#pragma unroll
    for (int r = 0; r < 4; r++) {
        int rr = r0 + r;
        di[r] = dinv[rr < n ? rr : 0];
    }
    bool odd = lane & 1;
#pragma unroll
    for (int ct = 0; ct < 3; ct++) {
        float x0 = acc[ct][0], x1 = acc[ct][1], x2 = acc[ct][2], x3 = acc[ct][3];
        float y0 = __shfl_xor(x0, 1, 64), y1 = __shfl_xor(x1, 1, 64);
        float y2 = __shfl_xor(x2, 1, 64), y3 = __shfl_xor(x3, 1, 64);
        int colp = ct * 16 + (c & ~1);
        if (colp >= 40) continue;
        if (!odd) {
            if (r0 + 0 < n) *(uint32_t*)(&G[(size_t)(r0 + 0) * 40 + colp]) = pack2bf(di[0] * x0, di[0] * y0);
            if (r0 + 1 < n) *(uint32_t*)(&G[(size_t)(r0 + 1) * 40 + colp]) = pack2bf(di[1] * x1, di[1] * y1);
        } else {
            if (r0 + 2 < n) *(uint32_t*)(&G[(size_t)(r0 + 2) * 40 + colp]) = pack2bf(di[2] * y2, di[2] * x2);
            if (r0 + 3 < n) *(uint32_t*)(&G[(size_t)(r0 + 3) * 40 + colp]) = pack2bf(di[3] * y3, di[3] * x3);
        }
    }
}

// ---------- D4/D6: unified 128-wide aggregate (G pre-scaled), 2-deep pipeline ----------
// wave = node; h = lane>>5 edge slot, fl = lane&31 uint2 in the 256B row.
// Two predicated 8-edge batches per iteration, all 8 gathers issued before
// batch-A FMAs (64 cache lines in flight/wave). Second batch skipped by
// wave-uniform branch -> padding waste stays at 8-granularity.
__global__ __launch_bounds__(256) void agg128(const unsigned short* __restrict__ G,
                                              const int* __restrict__ row_ptr,
                                              const int* __restrict__ deg,
                                              const unsigned short* __restrict__ csr_src,
                                              const float* __restrict__ dinv,
                                              const float* __restrict__ b,
                                              unsigned short* __restrict__ Y, int n) {
    int node = blockIdx.x * 4 + (threadIdx.x >> 6);
    if (node >= n) return;
    int l = threadIdx.x & 63;
    int h = l >> 5, fl = l & 31;
    const uint2* Gr = (const uint2*)G;

    float4 acc = make_float4(0.f, 0.f, 0.f, 0.f);
    if (h == 0) {
        uint2 sq = Gr[(size_t)node * 32 + fl];
        float2 a0 = bfp2f2(sq.x), a1 = bfp2f2(sq.y);
        acc = make_float4(a0.x, a0.y, a1.x, a1.y);  // self (pre-scaled)
    }
    int p = row_ptr[node];
    int p1 = p + deg[node];
    for (int q = p; q < p1; q += 16) {
        int i0 = q + h, i1 = q + 2 + h, i2 = q + 4 + h, i3 = q + 6 + h;
        bool v0 = i0 < p1, v1 = i1 < p1, v2 = i2 < p1, v3 = i3 < p1;
        int s0 = csr_src[v0 ? i0 : p], s1 = csr_src[v1 ? i1 : p];
        int s2 = csr_src[v2 ? i2 : p], s3 = csr_src[v3 ? i3 : p];
        uint2 q0 = Gr[(size_t)s0 * 32 + fl], q1 = Gr[(size_t)s1 * 32 + fl];
        uint2 q2 = Gr[(size_t)s2 * 32 + fl], q3 = Gr[(size_t)s3 * 32 + fl];
        bool hasB = (q + 8) < p1;
        uint2 q4, q5, q6, q7;
        bool v4 = false, v5 = false, v6 = false, v7 = false;
        if (hasB) {
            int i4 = q + 8 + h, i5 = q + 10 + h, i6 = q + 12 + h, i7 = q + 14 + h;
            v4 = i4 < p1; v5 = i5 < p1; v6 = i6 < p1; v7 = i7 < p1;
            int s4 = csr_src[v4 ? i4 : p], s5 = csr_src[v5 ? i5 : p];
            int s6 = csr_src[v6 ? i6 : p], s7 = csr_src[v7 ? i7 : p];
            q4 = Gr[(size_t)s4 * 32 + fl]; q5 = Gr[(size_t)s5 * 32 + fl];
            q6 = Gr[(size_t)s6 * 32 + fl]; q7 = Gr[(size_t)s7 * 32 + fl];
        }
        {
            float w0 = v0 ? 1.f : 0.f, w1 = v1 ? 1.f : 0.f;
            float w2 = v2 ? 1.f : 0.f, w3 = v3 ? 1.f : 0.f;
            float2 x0 = bfp2f2(q0.x), y0 = bfp2f2(q0.y);
            float2 x1 = bfp2f2(q1.x), y1 = bfp2f2(q1.y);
            float2 x2 = bfp2f2(q2.x), y2 = bfp2f2(q2.y);
            float2 x3 = bfp2f2(q3.x), y3 = bfp2f2(q3.y);
            acc.x += fmaf(w0, x0.x, w1 * x1.x) + fmaf(w2, x2.x, w3 * x3.x);
            acc.y += fmaf(w0, x0.y, w1 * x1.y) + fmaf(w2, x2.y, w3 * x3.y);
            acc.z += fmaf(w0, y0.x, w1 * y1.x) + fmaf(w2, y2.x, w3 * y3.x);
            acc.w += fmaf(w0, y0.y, w1 * y1.y) + fmaf(w2, y2.y, w3 * y3.y);
        }
        if (hasB) {
            float w4 = v4 ? 1.f : 0.f, w5 = v5 ? 1.f : 0.f;
            float w6 = v6 ? 1.f : 0.f, w7 = v7 ? 1.f : 0.f;
            float2 x4 = bfp2f2(q4.x), y4 = bfp2f2(q4.y);
            float2 x5 = bfp2f2(q5.x), y5 = bfp2f2(q5.y);
            float2 x6 = bfp2f2(q6.x), y6 = bfp2f2(q6.y);
            float2 x7 = bfp2f2(q7.x), y7 = bfp2f2(q7.y);
            acc.x += fmaf(w4, x4.x, w5 * x5.x) + fmaf(w6, x6.x, w7 * x7.x);
            acc.y += fmaf(w4, x4.y, w5 * x5.y) + fmaf(w6, x6.y, w7 * x7.y);
            acc.z += fmaf(w4, y4.x, w5 * y5.x) + fmaf(w6, y6.x, w7 * y7.x);
            acc.w += fmaf(w4, y4.y, w5 * y5.y) + fmaf(w6, y6.y, w7 * y7.y);
        }
    }
    acc.x += __shfl_xor(acc.x, 32, 64);
    acc.y += __shfl_xor(acc.y, 32, 64);
    acc.z += __shfl_xor(acc.z, 32, 64);
    acc.w += __shfl_xor(acc.w, 32, 64);
    float dn = dinv[node];
    float4 bb = ((const float4*)b)[fl];
    float r0 = fmaf(dn, acc.x, bb.x);
    float r1 = fmaf(dn, acc.y, bb.y);
    float r2 = fmaf(dn, acc.z, bb.z);
    float r3 = fmaf(dn, acc.w, bb.w);
    if (h == 0) {
        uint2 o;
        o.x = pack2bf(r0 > 0.f ? r0 : 0.f, r1 > 0.f ? r1 : 0.f);
        o.y = pack2bf(r2 > 0.f ? r2 : 0.f, r3 > 0.f ? r3 : 0.f);
        ((uint2*)Y)[(size_t)node * 32 + fl] = o;
    }
}

// ---------- D8: 40-wide aggregate + log_softmax, uint2 gather ----------
__global__ __launch_bounds__(256) void agg40_lsm(const unsigned short* __restrict__ G,
                                                 const int* __restrict__ row_ptr,
                                                 const int* __restrict__ deg,
                                                 const unsigned short* __restrict__ csr_src,
                                                 const float* __restrict__ dinv,
                                                 const float* __restrict__ b,
                                                 float* __restrict__ Y, int n) {
    int node = blockIdx.x * 4 + (threadIdx.x >> 6);
    if (node >= n) return;
    int l = threadIdx.x & 63;
    int h = l >> 5, fl = l & 31;
    bool act = fl < 10;
    int flc = act ? fl : 0;
    const uint2* Gr = (const uint2*)G;  // row = 10 uint2 (80B)

    float4 acc = make_float4(0.f, 0.f, 0.f, 0.f);
    if (h == 0) {
        uint2 sq = Gr[(size_t)node * 10 + flc];
        float2 a0 = bfp2f2(sq.x), a1 = bfp2f2(sq.y);
        acc = make_float4(a0.x, a0.y, a1.x, a1.y);  // self (pre-scaled)
    }
    int p = row_ptr[node];
    int p1 = p + deg[node];
    for (int q = p; q < p1; q += 8) {
        int i0 = q + h, i1 = q + 2 + h, i2 = q + 4 + h, i3 = q + 6 + h;
        bool v0 = i0 < p1, v1 = i1 < p1, v2 = i2 < p1, v3 = i3 < p1;
        int s0 = csr_src[v0 ? i0 : p], s1 = csr_src[v1 ? i1 : p];
        int s2 = csr_src[v2 ? i2 : p], s3 = csr_src[v3 ? i3 : p];
        float d0 = v0 ? 1.f : 0.f, d1 = v1 ? 1.f : 0.f;
        float d2 = v2 ? 1.f : 0.f, d3 = v3 ? 1.f : 0.f;
        uint2 q0 = Gr[(size_t)s0 * 10 + flc], q1 = Gr[(size_t)s1 * 10 + flc];
        uint2 q2 = Gr[(size_t)s2 * 10 + flc], q3 = Gr[(size_t)s3 * 10 + flc];
        float2 x0 = bfp2f2(q0.x), y0 = bfp2f2(q0.y);
        float2 x1 = bfp2f2(q1.x), y1 = bfp2f2(q1.y);
        float2 x2 = bfp2f2(q2.x), y2 = bfp2f2(q2.y);
        float2 x3 = bfp2f2(q3.x), y3 = bfp2f2(q3.y);
        acc.x += fmaf(d0, x0.x, d1 * x1.x) + fmaf(d2, x2.x, d3 * x3.x);
        acc.y += fmaf(d0, x0.y, d1 * x1.y) + fmaf(d2, x2.y, d3 * x3.y);
        acc.z += fmaf(d0, y0.x, d1 * y1.x) + fmaf(d2, y2.x, d3 * y3.x);
        acc.w += fmaf(d0, y0.y, d1 * y1.y) + fmaf(d2, y2.y, d3 * y3.y);
    }
    acc.x += __shfl_xor(acc.x, 32, 64);
    acc.y += __shfl_xor(acc.y, 32, 64);
    acc.z += __shfl_xor(acc.z, 32, 64);
    acc.w += __shfl_xor(acc.w, 32, 64);
    float dn = dinv[node];
    const float4* b4 = (const float4*)b;  // 40 floats = 10 float4
    float4 bb = b4[flc];
    float v0_ = fmaf(dn, acc.x, bb.x);
    float v1_ = fmaf(dn, acc.y, bb.y);
    float v2_ = fmaf(dn, acc.z, bb.z);
    float v3_ = fmaf(dn, acc.w, bb.w);
    float m = act ? fmaxf(fmaxf(v0_, v1_), fmaxf(v2_, v3_)) : -1e30f;
#pragma unroll
    for (int off = 8; off > 0; off >>= 1) m = fmaxf(m, __shfl_xor(m, off, 16));
    float e0 = act ? expf(v0_ - m) : 0.f;
    float e1 = act ? expf(v1_ - m) : 0.f;
    float e2 = act ? expf(v2_ - m) : 0.f;
    float e3 = act ? expf(v3_ - m) : 0.f;
    float s_ = ((e0 + e1) + (e2 + e3));
#pragma unroll
    for (int off = 8; off > 0; off >>= 1) s_ += __shfl_xor(s_, off, 16);
    float ls = logf(s_) + m;
    if (h == 0 && act) {
        float4 o = make_float4(v0_ - ls, v1_ - ls, v2_ - ls, v3_ - ls);
        ((float4*)Y)[(size_t)node * 10 + fl] = o;
    }
}

// ---------- launch ----------

extern "C" void kernel_launch(void* const* d_in, const int* in_sizes, int n_in,
                              void* d_out, int out_size, void* d_ws, size_t ws_size,
                              hipStream_t stream) {
    const float* x  = (const float*)d_in[0];
    const int*   ei = (const int*)d_in[1];
    const float* W1 = (const float*)d_in[2];
    const float* b1 = (const float*)d_in[3];
    const float* W2 = (const float*)d_in[4];
    const float* b2 = (const float*)d_in[5];
    const float* W3 = (const float*)d_in[6];
    const float* b3 = (const float*)d_in[7];
    float* out = (float*)d_out;

    const int n = NN, e = NE;
    const int* srcI = ei;
    const int* dstI = ei + e;

    char* ws = (char*)d_ws;
    int*            deg     = (int*)ws;                          // n ints
    int*            row_ptr = (int*)(ws + 200704);               // n ints
    float*          dinv    = (float*)(ws + 401408);             // n fp32
    int*            cursor  = (int*)(ws + 602112);               // NB ints
    uint32_t*       packA   = (uint32_t*)(ws + 603136);          // NB*SLAB uint32 (6.4MB)
    unsigned short* csr_src = (unsigned short*)(ws + 7025664);   // E ushort (1.6MB)
    unsigned short* WT1     = (unsigned short*)(ws + 8625664);   // 128x128 bf16
    unsigned short* WT2     = (unsigned short*)(ws + 8658432);
    unsigned short* WT3     = (unsigned short*)(ws + 8691200);   // 48x128 bf16
    unsigned short* bufG    = (unsigned short*)(ws + 8703488);   // n*128 bf16
    unsigned short* bufA    = (unsigned short*)(ws + 21503488);  // n*128 bf16

    // D1: W transposes + zero cursors
    prep<<<153, 256, 0, stream>>>(W1, W2, W3, WT1, WT2, WT3, cursor);
    // D2: layer-1 GEMM (unscaled) ∪ slab scatter
    gemm1_hist<<<GG + SB, 256, 0, stream>>>(x, WT1, bufG, n, srcI, dstI, cursor, packA, e);
    // D3: per-bucket sort -> CSR + row_ptr/deg/dinv + H1 pre-scale
    buildB<<<NB, 256, 0, stream>>>(packA, cursor, row_ptr, deg, dinv, csr_src, bufG, n);
    // D4: aggregate layer 1 (pre-scaled, unified kernel)
    agg128<<<(n + 3) / 4, 256, 0, stream>>>(bufG, row_ptr, deg, csr_src, dinv, b1, bufA, n);
    // D5: layer-2 GEMM (pre-scaled)
    gemm128_mfma<<<GG, 256, 0, stream>>>(bufA, WT2, dinv, bufG, n);
    // D6: aggregate layer 2
    agg128<<<(n + 3) / 4, 256, 0, stream>>>(bufG, row_ptr, deg, csr_src, dinv, b2, bufA, n);
    // D7: layer-3 GEMM (40-wide, pre-scaled)
    gemm40_mfma<<<GG, 256, 0, stream>>>(bufA, WT3, dinv, bufG, n);
    // D8: aggregate + log_softmax -> out
    agg40_lsm<<<(n + 3) / 4, 256, 0, stream>>>(bufG, row_ptr, deg, csr_src, dinv, b3, out, n);
}

// Round 9
// 270.369 us; speedup vs baseline: 1.3210x; 1.0335x over previous
//
#include <hip/hip_runtime.h>
#include <stdint.h>

#define NN 50000
#define NE 800000
#define GG 782     // gemm grid: (NN + 63) / 64
#define NB 196     // hi buckets: ceil(NN / 256)
#define TT 2048    // edges per scatter block
#define SB 391     // scatter blocks: ceil(NE / TT)
#define SLAB 8192  // packA slab stride per bucket

typedef __attribute__((ext_vector_type(8))) short bfx8;   // 8 bf16 (4 VGPRs)
typedef __attribute__((ext_vector_type(4))) float f32x4;  // MFMA acc

// ---- bf16 helpers (RNE) ----
__device__ inline unsigned short f2bf(float f) {
    union { float f; uint32_t u; } x; x.f = f;
    uint32_t u = x.u;
    return (unsigned short)((u + 0x7fffu + ((u >> 16) & 1u)) >> 16);
}
__device__ inline uint32_t pack2bf(float lo, float hi) {
    return (uint32_t)f2bf(lo) | ((uint32_t)f2bf(hi) << 16);
}
__device__ inline float bf2f(unsigned short h) {
    union { uint32_t u; float f; } c; c.u = ((uint32_t)h) << 16;
    return c.f;
}
__device__ inline float2 bfp2f2(uint32_t v) {
    union { uint32_t u; float f; } a, b;
    a.u = (v & 0xffffu) << 16;
    b.u = v & 0xffff0000u;
    return make_float2(a.f, b.f);
}
__device__ inline bfx8 ld8(const unsigned short* p) {
    union { uint4 u; bfx8 v; } c;
    c.u = *(const uint4*)p;
    return c.v;
}
__device__ inline bfx8 cvt8(float4 u, float4 v) {
    union { unsigned short s[8]; bfx8 r; } c;
    c.s[0] = f2bf(u.x); c.s[1] = f2bf(u.y); c.s[2] = f2bf(u.z); c.s[3] = f2bf(u.w);
    c.s[4] = f2bf(v.x); c.s[5] = f2bf(v.y); c.s[6] = f2bf(v.z); c.s[7] = f2bf(v.w);
    return c.r;
}

// ---------- D1: W transposes + zero bucket cursors ----------
__global__ void prep(const float* __restrict__ W1, const float* __restrict__ W2,
                     const float* __restrict__ W3,
                     unsigned short* __restrict__ WT1, unsigned short* __restrict__ WT2,
                     unsigned short* __restrict__ WT3, int* __restrict__ cursor) {
    if (blockIdx.x == 152) {
        if (threadIdx.x < NB) cursor[threadIdx.x] = 0;
        return;
    }
    int w = blockIdx.x * 256 + threadIdx.x;
    if (w < 16384) {
        int nn = w >> 7, k = w & 127;
        WT1[nn * 128 + k] = f2bf(W1[k * 128 + nn]);
    } else if (w < 32768) {
        int w2 = w - 16384, nn = w2 >> 7, k = w2 & 127;
        WT2[nn * 128 + k] = f2bf(W2[k * 128 + nn]);
    } else if (w < 38912) {
        int w2 = w - 32768, nn = w2 >> 7, k = w2 & 127;  // 48x128, zero-pad
        WT3[nn * 128 + k] = (nn < 40) ? f2bf(W3[k * 40 + nn]) : (unsigned short)0;
    }
}

// ---------- D2: layer-1 GEMM ∪ bucket-scatter (cursor-reservation) ----------
__global__ __launch_bounds__(256) void gemm1_hist(const float* __restrict__ X,
                                                  const unsigned short* __restrict__ WT,
                                                  unsigned short* __restrict__ G, int n,
                                                  const int* __restrict__ src,
                                                  const int* __restrict__ dst,
                                                  int* __restrict__ cursor,
                                                  uint32_t* __restrict__ packA, int e) {
    __shared__ int lc[NB];
    __shared__ int gb[NB];
    if (blockIdx.x >= GG) {
        int b = blockIdx.x - GG;
        int t = threadIdx.x;
        if (t < NB) lc[t] = 0;
        __syncthreads();
        int start = b * TT;
        int end = start + TT; if (end > e) end = e;
        int hi_[8], r_[8];
        uint32_t pk_[8];
#pragma unroll
        for (int j = 0; j < 8; j++) {
            int i = start + j * 256 + t;
            if (i < end) {
                int dd = dst[i], ss = src[i];
                hi_[j] = dd >> 8;
                pk_[j] = ((uint32_t)dd << 16) | (uint32_t)ss;
                r_[j] = atomicAdd(&lc[hi_[j]], 1);  // LDS rank
            } else r_[j] = -1;
        }
        __syncthreads();
        if (t < NB) {
            int c = lc[t];
            gb[t] = c ? atomicAdd(&cursor[t], c) : 0;  // global slab reservation
        }
        __syncthreads();
#pragma unroll
        for (int j = 0; j < 8; j++) {
            if (r_[j] >= 0)
                packA[(size_t)hi_[j] * SLAB + gb[hi_[j]] + r_[j]] = pk_[j];
        }
        return;
    }
    int wave = threadIdx.x >> 6;
    int lane = threadIdx.x & 63;
    int quad = lane >> 4;
    int c = lane & 15;
    int rowbase = blockIdx.x * 64 + wave * 16;

    int arow = rowbase + c;
    if (arow >= n) arow = n - 1;
    const float* ap = X + (size_t)arow * 128 + quad * 8;
    bfx8 a[4];
#pragma unroll
    for (int kc = 0; kc < 4; kc++) {
        float4 u = *(const float4*)(ap + kc * 32);
        float4 v = *(const float4*)(ap + kc * 32 + 4);
        a[kc] = cvt8(u, v);
    }

    f32x4 acc[8];
#pragma unroll
    for (int ct = 0; ct < 8; ct++) acc[ct] = (f32x4){0.f, 0.f, 0.f, 0.f};
#pragma unroll
    for (int ct = 0; ct < 8; ct++) {
        const unsigned short* bp = WT + (size_t)(ct * 16 + c) * 128 + quad * 8;
#pragma unroll
        for (int kc = 0; kc < 4; kc++) {
            bfx8 b = ld8(bp + kc * 32);
            acc[ct] = __builtin_amdgcn_mfma_f32_16x16x32_bf16(a[kc], b, acc[ct], 0, 0, 0);
        }
    }

    int r0 = rowbase + quad * 4;
    bool odd = lane & 1;
#pragma unroll
    for (int ct = 0; ct < 8; ct++) {
        float x0 = acc[ct][0], x1 = acc[ct][1], x2 = acc[ct][2], x3 = acc[ct][3];
        float y0 = __shfl_xor(x0, 1, 64), y1 = __shfl_xor(x1, 1, 64);
        float y2 = __shfl_xor(x2, 1, 64), y3 = __shfl_xor(x3, 1, 64);
        int colp = ct * 16 + (c & ~1);
        if (!odd) {
            if (r0 + 0 < n) *(uint32_t*)(&G[(size_t)(r0 + 0) * 128 + colp]) = pack2bf(x0, y0);
            if (r0 + 1 < n) *(uint32_t*)(&G[(size_t)(r0 + 1) * 128 + colp]) = pack2bf(x1, y1);
        } else {
            if (r0 + 2 < n) *(uint32_t*)(&G[(size_t)(r0 + 2) * 128 + colp]) = pack2bf(y2, x2);
            if (r0 + 3 < n) *(uint32_t*)(&G[(size_t)(r0 + 3) * 128 + colp]) = pack2bf(y3, x3);
        }
    }
}

// ---------- D3: per-bucket fine sort -> row_ptr/deg/dinv + csr_src ----------
__global__ __launch_bounds__(256) void buildB(const uint32_t* __restrict__ packA,
                                              const int* __restrict__ cursor,
                                              int* __restrict__ row_ptr, int* __restrict__ deg,
                                              float* __restrict__ dinv,
                                              unsigned short* __restrict__ csr_src, int n) {
    __shared__ int s[256];
    __shared__ int cnt[256];
    __shared__ int rp[256];
    __shared__ int basehi, bcnt;
    int hi = blockIdx.x;
    int t = threadIdx.x;
    int bc = (t < NB) ? cursor[t] : 0;
    s[t] = bc;
    __syncthreads();
#pragma unroll
    for (int off = 1; off < 256; off <<= 1) {
        int y = (t >= off) ? s[t - off] : 0;
        __syncthreads();
        s[t] += y;
        __syncthreads();
    }
    if (t == hi) { basehi = s[t] - bc; bcnt = bc; }
    cnt[t] = 0;
    __syncthreads();
    int b0 = basehi;
    int mc = bcnt;
    const uint32_t* slab = packA + (size_t)hi * SLAB;
    for (int i = t; i < mc; i += 256)
        atomicAdd(&cnt[(slab[i] >> 16) & 0xFF], 1);  // LDS
    __syncthreads();
    int v = cnt[t];
    s[t] = v;
    __syncthreads();
#pragma unroll
    for (int off = 1; off < 256; off <<= 1) {
        int y = (t >= off) ? s[t - off] : 0;
        __syncthreads();
        s[t] += y;
        __syncthreads();
    }
    rp[t] = b0 + s[t] - v;  // absolute row start for node hi*256+t
    int node = hi * 256 + t;
    if (node < n) {
        row_ptr[node] = rp[t];
        deg[node] = v;
        dinv[node] = rsqrtf(1.0f + (float)v);
    }
    cnt[t] = 0;
    __syncthreads();
    for (int i = t; i < mc; i += 256) {
        uint32_t p = slab[i];
        int lo = (p >> 16) & 0xFF;
        int r = atomicAdd(&cnt[lo], 1);  // LDS
        csr_src[rp[lo] + r] = (unsigned short)(p & 0xFFFF);
    }
}

// ---------- GEMMs for layers 2/3: pre-scale rows by dinv (epilogue) ----------
__global__ __launch_bounds__(256) void gemm128_mfma(const unsigned short* __restrict__ A,
                                                    const unsigned short* __restrict__ WT,
                                                    const float* __restrict__ dinv,
                                                    unsigned short* __restrict__ G, int n) {
    int wave = threadIdx.x >> 6;
    int lane = threadIdx.x & 63;
    int quad = lane >> 4;
    int c = lane & 15;
    int rowbase = blockIdx.x * 64 + wave * 16;

    int arow = rowbase + c;
    if (arow >= n) arow = n - 1;
    const unsigned short* ap = A + (size_t)arow * 128 + quad * 8;
    bfx8 a[4];
#pragma unroll
    for (int kc = 0; kc < 4; kc++) a[kc] = ld8(ap + kc * 32);

    f32x4 acc[8];
#pragma unroll
    for (int ct = 0; ct < 8; ct++) acc[ct] = (f32x4){0.f, 0.f, 0.f, 0.f};
#pragma unroll
    for (int ct = 0; ct < 8; ct++) {
        const unsigned short* bp = WT + (size_t)(ct * 16 + c) * 128 + quad * 8;
#pragma unroll
        for (int kc = 0; kc < 4; kc++) {
            bfx8 b = ld8(bp + kc * 32);
            acc[ct] = __builtin_amdgcn_mfma_f32_16x16x32_bf16(a[kc], b, acc[ct], 0, 0, 0);
        }
    }

    int r0 = rowbase + quad * 4;
    float di[4];
#pragma unroll
    for (int r = 0; r < 4; r++) {
        int rr = r0 + r;
        di[r] = dinv[rr < n ? rr : 0];
    }
    bool odd = lane & 1;
#pragma unroll
    for (int ct = 0; ct < 8; ct++) {
        float x0 = acc[ct][0], x1 = acc[ct][1], x2 = acc[ct][2], x3 = acc[ct][3];
        float y0 = __shfl_xor(x0, 1, 64), y1 = __shfl_xor(x1, 1, 64);
        float y2 = __shfl_xor(x2, 1, 64), y3 = __shfl_xor(x3, 1, 64);
        int colp = ct * 16 + (c & ~1);
        if (!odd) {
            if (r0 + 0 < n) *(uint32_t*)(&G[(size_t)(r0 + 0) * 128 + colp]) = pack2bf(di[0] * x0, di[0] * y0);
            if (r0 + 1 < n) *(uint32_t*)(&G[(size_t)(r0 + 1) * 128 + colp]) = pack2bf(di[1] * x1, di[1] * y1);
        } else {
            if (r0 + 2 < n) *(uint32_t*)(&G[(size_t)(r0 + 2) * 128 + colp]) = pack2bf(di[2] * y2, di[2] * x2);
            if (r0 + 3 < n) *(uint32_t*)(&G[(size_t)(r0 + 3) * 128 + colp]) = pack2bf(di[3] * y3, di[3] * x3);
        }
    }
}

__global__ __launch_bounds__(256) void gemm40_mfma(const unsigned short* __restrict__ A,
                                                   const unsigned short* __restrict__ WT,
                                                   const float* __restrict__ dinv,
                                                   unsigned short* __restrict__ G, int n) {
    int wave = threadIdx.x >> 6;
    int lane = threadIdx.x & 63;
    int quad = lane >> 4;
    int c = lane & 15;
    int rowbase = blockIdx.x * 64 + wave * 16;

    int arow = rowbase + c;
    if (arow >= n) arow = n - 1;
    const unsigned short* ap = A + (size_t)arow * 128 + quad * 8;
    bfx8 a[4];
#pragma unroll
    for (int kc = 0; kc < 4; kc++) a[kc] = ld8(ap + kc * 32);

    f32x4 acc[3];
#pragma unroll
    for (int ct = 0; ct < 3; ct++) acc[ct] = (f32x4){0.f, 0.f, 0.f, 0.f};
#pragma unroll
    for (int ct = 0; ct < 3; ct++) {
        const unsigned short* bp = WT + (size_t)(ct * 16 + c) * 128 + quad * 8;
#pragma unroll
        for (int kc = 0; kc < 4; kc++) {
            bfx8 b = ld8(bp + kc * 32);
            acc[ct] = __builtin_amdgcn_mfma_f32_16x16x32_bf16(a[kc], b, acc[ct], 0, 0, 0);
        }
    }

    int r0 = rowbase + quad * 4;
    float di[4];
#pragma unroll
    for (int r = 0; r < 4; r++) {
        int rr = r0 + r;
        di[r] = dinv[rr < n ? rr : 0];
    }
    bool odd = lane & 1;
#pragma unroll
    for (int ct = 0; ct < 3; ct++) {
        float x0 = acc[ct][0], x1 = acc[ct][1], x2 = acc[ct][2], x3 = acc[ct][3];
        float y0 = __shfl_xor(x0, 1, 64), y1 = __shfl_xor(x1, 1, 64);
        float y2 = __shfl_xor(x2, 1, 64), y3 = __shfl_xor(x3, 1, 64);
        int colp = ct * 16 + (c & ~1);
        if (colp >= 40) continue;
        if (!odd) {
            if (r0 + 0 < n) *(uint32_t*)(&G[(size_t)(r0 + 0) * 40 + colp]) = pack2bf(di[0] * x0, di[0] * y0);
            if (r0 + 1 < n) *(uint32_t*)(&G[(size_t)(r0 + 1) * 40 + colp]) = pack2bf(di[1] * x1, di[1] * y1);
        } else {
            if (r0 + 2 < n) *(uint32_t*)(&G[(size_t)(r0 + 2) * 40 + colp]) = pack2bf(di[2] * y2, di[2] * x2);
            if (r0 + 3 < n) *(uint32_t*)(&G[(size_t)(r0 + 3) * 40 + colp]) = pack2bf(di[3] * y3, di[3] * x3);
        }
    }
}

// ---------- D4: layer-1 aggregate, uint2 gather (2 edges per load instr) ----------
// wave = node; h = lane>>5 is the edge slot, fl = lane&31 the uint2 within the
// 256B row. One 64-lane dwordx2 load fetches TWO edges' rows (512B). 4 loads
// in flight per 8-edge batch. Per-edge dinv[s] weights (H1 is unscaled).
// ~48us: L2-capacity wall (12.8MB > 4MB/XCD L2; 60% hit, 83MB miss traffic).
// Measured invariant to ILP depth, load width, and extra load streams (R3/R5/R8).
__global__ __launch_bounds__(256) void agg128_l1(const unsigned short* __restrict__ G,
                                                 const int* __restrict__ row_ptr,
                                                 const int* __restrict__ deg,
                                                 const unsigned short* __restrict__ csr_src,
                                                 const float* __restrict__ dinv,
                                                 const float* __restrict__ b,
                                                 unsigned short* __restrict__ Y, int n) {
    int node = blockIdx.x * 4 + (threadIdx.x >> 6);
    if (node >= n) return;
    int l = threadIdx.x & 63;
    int h = l >> 5, fl = l & 31;
    const uint2* Gr = (const uint2*)G;  // row = 32 uint2 (256B)

    float dn = dinv[node];
    float4 acc = make_float4(0.f, 0.f, 0.f, 0.f);
    if (h == 0) {
        uint2 sq = Gr[(size_t)node * 32 + fl];
        float2 a0 = bfp2f2(sq.x), a1 = bfp2f2(sq.y);
        acc = make_float4(dn * a0.x, dn * a0.y, dn * a1.x, dn * a1.y);  // self
    }
    int p = row_ptr[node];
    int p1 = p + deg[node];
    for (int q = p; q < p1; q += 8) {
        int i0 = q + h, i1 = q + 2 + h, i2 = q + 4 + h, i3 = q + 6 + h;
        bool v0 = i0 < p1, v1 = i1 < p1, v2 = i2 < p1, v3 = i3 < p1;
        int s0 = csr_src[v0 ? i0 : p], s1 = csr_src[v1 ? i1 : p];
        int s2 = csr_src[v2 ? i2 : p], s3 = csr_src[v3 ? i3 : p];
        float d0 = v0 ? dinv[s0] : 0.f, d1 = v1 ? dinv[s1] : 0.f;
        float d2 = v2 ? dinv[s2] : 0.f, d3 = v3 ? dinv[s3] : 0.f;
        uint2 q0 = Gr[(size_t)s0 * 32 + fl], q1 = Gr[(size_t)s1 * 32 + fl];
        uint2 q2 = Gr[(size_t)s2 * 32 + fl], q3 = Gr[(size_t)s3 * 32 + fl];
        float2 x0 = bfp2f2(q0.x), y0 = bfp2f2(q0.y);
        float2 x1 = bfp2f2(q1.x), y1 = bfp2f2(q1.y);
        float2 x2 = bfp2f2(q2.x), y2 = bfp2f2(q2.y);
        float2 x3 = bfp2f2(q3.x), y3 = bfp2f2(q3.y);
        acc.x += fmaf(d0, x0.x, d1 * x1.x) + fmaf(d2, x2.x, d3 * x3.x);
        acc.y += fmaf(d0, x0.y, d1 * x1.y) + fmaf(d2, x2.y, d3 * x3.y);
        acc.z += fmaf(d0, y0.x, d1 * y1.x) + fmaf(d2, y2.x, d3 * y3.x);
        acc.w += fmaf(d0, y0.y, d1 * y1.y) + fmaf(d2, y2.y, d3 * y3.y);
    }
    acc.x += __shfl_xor(acc.x, 32, 64);
    acc.y += __shfl_xor(acc.y, 32, 64);
    acc.z += __shfl_xor(acc.z, 32, 64);
    acc.w += __shfl_xor(acc.w, 32, 64);
    float4 bb = ((const float4*)b)[fl];
    float r0 = fmaf(dn, acc.x, bb.x);
    float r1 = fmaf(dn, acc.y, bb.y);
    float r2 = fmaf(dn, acc.z, bb.z);
    float r3 = fmaf(dn, acc.w, bb.w);
    if (h == 0) {
        uint2 o;
        o.x = pack2bf(r0 > 0.f ? r0 : 0.f, r1 > 0.f ? r1 : 0.f);
        o.y = pack2bf(r2 > 0.f ? r2 : 0.f, r3 > 0.f ? r3 : 0.f);
        ((uint2*)Y)[(size_t)node * 32 + fl] = o;
    }
}

// ---------- D6: layer-2 aggregate, uint2 gather (G pre-scaled) ----------
__global__ __launch_bounds__(256) void agg128(const unsigned short* __restrict__ G,
                                              const int* __restrict__ row_ptr,
                                              const int* __restrict__ deg,
                                              const unsigned short* __restrict__ csr_src,
                                              const float* __restrict__ dinv,
                                              const float* __restrict__ b,
                                              unsigned short* __restrict__ Y, int n) {
    int node = blockIdx.x * 4 + (threadIdx.x >> 6);
    if (node >= n) return;
    int l = threadIdx.x & 63;
    int h = l >> 5, fl = l & 31;
    const uint2* Gr = (const uint2*)G;

    float4 acc = make_float4(0.f, 0.f, 0.f, 0.f);
    if (h == 0) {
        uint2 sq = Gr[(size_t)node * 32 + fl];
        float2 a0 = bfp2f2(sq.x), a1 = bfp2f2(sq.y);
        acc = make_float4(a0.x, a0.y, a1.x, a1.y);  // self (pre-scaled)
    }
    int p = row_ptr[node];
    int p1 = p + deg[node];
    for (int q = p; q < p1; q += 8) {
        int i0 = q + h, i1 = q + 2 + h, i2 = q + 4 + h, i3 = q + 6 + h;
        bool v0 = i0 < p1, v1 = i1 < p1, v2 = i2 < p1, v3 = i3 < p1;
        int s0 = csr_src[v0 ? i0 : p], s1 = csr_src[v1 ? i1 : p];
        int s2 = csr_src[v2 ? i2 : p], s3 = csr_src[v3 ? i3 : p];
        float d0 = v0 ? 1.f : 0.f, d1 = v1 ? 1.f : 0.f;
        float d2 = v2 ? 1.f : 0.f, d3 = v3 ? 1.f : 0.f;
        uint2 q0 = Gr[(size_t)s0 * 32 + fl], q1 = Gr[(size_t)s1 * 32 + fl];
        uint2 q2 = Gr[(size_t)s2 * 32 + fl], q3 = Gr[(size_t)s3 * 32 + fl];
        float2 x0 = bfp2f2(q0.x), y0 = bfp2f2(q0.y);
        float2 x1 = bfp2f2(q1.x), y1 = bfp2f2(q1.y);
        float2 x2 = bfp2f2(q2.x), y2 = bfp2f2(q2.y);
        float2 x3 = bfp2f2(q3.x), y3 = bfp2f2(q3.y);
        acc.x += fmaf(d0, x0.x, d1 * x1.x) + fmaf(d2, x2.x, d3 * x3.x);
        acc.y += fmaf(d0, x0.y, d1 * x1.y) + fmaf(d2, x2.y, d3 * x3.y);
        acc.z += fmaf(d0, y0.x, d1 * y1.x) + fmaf(d2, y2.x, d3 * y3.x);
        acc.w += fmaf(d0, y0.y, d1 * y1.y) + fmaf(d2, y2.y, d3 * y3.y);
    }
    acc.x += __shfl_xor(acc.x, 32, 64);
    acc.y += __shfl_xor(acc.y, 32, 64);
    acc.z += __shfl_xor(acc.z, 32, 64);
    acc.w += __shfl_xor(acc.w, 32, 64);
    float dn = dinv[node];
    float4 bb = ((const float4*)b)[fl];
    float r0 = fmaf(dn, acc.x, bb.x);
    float r1 = fmaf(dn, acc.y, bb.y);
    float r2 = fmaf(dn, acc.z, bb.z);
    float r3 = fmaf(dn, acc.w, bb.w);
    if (h == 0) {
        uint2 o;
        o.x = pack2bf(r0 > 0.f ? r0 : 0.f, r1 > 0.f ? r1 : 0.f);
        o.y = pack2bf(r2 > 0.f ? r2 : 0.f, r3 > 0.f ? r3 : 0.f);
        ((uint2*)Y)[(size_t)node * 32 + fl] = o;
    }
}

// ---------- D8: 40-wide aggregate + log_softmax, uint2 gather ----------
// Row = 40 bf16 = 10 uint2. Lanes fl<10 active; 2 edges per instruction.
// G40 = 4MB: fits per-XCD L2 -> ~2x the per-line service rate of the
// 128-wide aggs (measured; confirms the L2-capacity model).
__global__ __launch_bounds__(256) void agg40_lsm(const unsigned short* __restrict__ G,
                                                 const int* __restrict__ row_ptr,
                                                 const int* __restrict__ deg,
                                                 const unsigned short* __restrict__ csr_src,
                                                 const float* __restrict__ dinv,
                                                 const float* __restrict__ b,
                                                 float* __restrict__ Y, int n) {
    int node = blockIdx.x * 4 + (threadIdx.x >> 6);
    if (node >= n) return;
    int l = threadIdx.x & 63;
    int h = l >> 5, fl = l & 31;
    bool act = fl < 10;
    int flc = act ? fl : 0;
    const uint2* Gr = (const uint2*)G;  // row = 10 uint2 (80B)

    float4 acc = make_float4(0.f, 0.f, 0.f, 0.f);
    if (h == 0) {
        uint2 sq = Gr[(size_t)node * 10 + flc];
        float2 a0 = bfp2f2(sq.x), a1 = bfp2f2(sq.y);
        acc = make_float4(a0.x, a0.y, a1.x, a1.y);  // self (pre-scaled)
    }
    int p = row_ptr[node];
    int p1 = p + deg[node];
    for (int q = p; q < p1; q += 8) {
        int i0 = q + h, i1 = q + 2 + h, i2 = q + 4 + h, i3 = q + 6 + h;
        bool v0 = i0 < p1, v1 = i1 < p1, v2 = i2 < p1, v3 = i3 < p1;
        int s0 = csr_src[v0 ? i0 : p], s1 = csr_src[v1 ? i1 : p];
        int s2 = csr_src[v2 ? i2 : p], s3 = csr_src[v3 ? i3 : p];
        float d0 = v0 ? 1.f : 0.f, d1 = v1 ? 1.f : 0.f;
        float d2 = v2 ? 1.f : 0.f, d3 = v3 ? 1.f : 0.f;
        uint2 q0 = Gr[(size_t)s0 * 10 + flc], q1 = Gr[(size_t)s1 * 10 + flc];
        uint2 q2 = Gr[(size_t)s2 * 10 + flc], q3 = Gr[(size_t)s3 * 10 + flc];
        float2 x0 = bfp2f2(q0.x), y0 = bfp2f2(q0.y);
        float2 x1 = bfp2f2(q1.x), y1 = bfp2f2(q1.y);
        float2 x2 = bfp2f2(q2.x), y2 = bfp2f2(q2.y);
        float2 x3 = bfp2f2(q3.x), y3 = bfp2f2(q3.y);
        acc.x += fmaf(d0, x0.x, d1 * x1.x) + fmaf(d2, x2.x, d3 * x3.x);
        acc.y += fmaf(d0, x0.y, d1 * x1.y) + fmaf(d2, x2.y, d3 * x3.y);
        acc.z += fmaf(d0, y0.x, d1 * y1.x) + fmaf(d2, y2.x, d3 * y3.x);
        acc.w += fmaf(d0, y0.y, d1 * y1.y) + fmaf(d2, y2.y, d3 * y3.y);
    }
    acc.x += __shfl_xor(acc.x, 32, 64);
    acc.y += __shfl_xor(acc.y, 32, 64);
    acc.z += __shfl_xor(acc.z, 32, 64);
    acc.w += __shfl_xor(acc.w, 32, 64);
    float dn = dinv[node];
    const float4* b4 = (const float4*)b;  // 40 floats = 10 float4
    float4 bb = b4[flc];
    float v0_ = fmaf(dn, acc.x, bb.x);
    float v1_ = fmaf(dn, acc.y, bb.y);
    float v2_ = fmaf(dn, acc.z, bb.z);
    float v3_ = fmaf(dn, acc.w, bb.w);
    float m = act ? fmaxf(fmaxf(v0_, v1_), fmaxf(v2_, v3_)) : -1e30f;
#pragma unroll
    for (int off = 8; off > 0; off >>= 1) m = fmaxf(m, __shfl_xor(m, off, 16));
    float e0 = act ? expf(v0_ - m) : 0.f;
    float e1 = act ? expf(v1_ - m) : 0.f;
    float e2 = act ? expf(v2_ - m) : 0.f;
    float e3 = act ? expf(v3_ - m) : 0.f;
    float s_ = ((e0 + e1) + (e2 + e3));
#pragma unroll
    for (int off = 8; off > 0; off >>= 1) s_ += __shfl_xor(s_, off, 16);
    float ls = logf(s_) + m;
    if (h == 0 && act) {
        float4 o = make_float4(v0_ - ls, v1_ - ls, v2_ - ls, v3_ - ls);
        ((float4*)Y)[(size_t)node * 10 + fl] = o;
    }
}

// ---------- launch ----------

extern "C" void kernel_launch(void* const* d_in, const int* in_sizes, int n_in,
                              void* d_out, int out_size, void* d_ws, size_t ws_size,
                              hipStream_t stream) {
    const float* x  = (const float*)d_in[0];
    const int*   ei = (const int*)d_in[1];
    const float* W1 = (const float*)d_in[2];
    const float* b1 = (const float*)d_in[3];
    const float* W2 = (const float*)d_in[4];
    const float* b2 = (const float*)d_in[5];
    const float* W3 = (const float*)d_in[6];
    const float* b3 = (const float*)d_in[7];
    float* out = (float*)d_out;

    const int n = NN, e = NE;
    const int* srcI = ei;
    const int* dstI = ei + e;

    char* ws = (char*)d_ws;
    int*            deg     = (int*)ws;                          // n ints
    int*            row_ptr = (int*)(ws + 200704);               // n ints
    float*          dinv    = (float*)(ws + 401408);             // n fp32
    int*            cursor  = (int*)(ws + 602112);               // NB ints
    uint32_t*       packA   = (uint32_t*)(ws + 603136);          // NB*SLAB uint32 (6.4MB)
    unsigned short* csr_src = (unsigned short*)(ws + 7025664);   // E ushort (1.6MB)
    unsigned short* WT1     = (unsigned short*)(ws + 8625664);   // 128x128 bf16
    unsigned short* WT2     = (unsigned short*)(ws + 8658432);
    unsigned short* WT3     = (unsigned short*)(ws + 8691200);   // 48x128 bf16
    unsigned short* bufG    = (unsigned short*)(ws + 8703488);   // n*128 bf16
    unsigned short* bufA    = (unsigned short*)(ws + 21503488);  // n*128 bf16

    // D1: W transposes + zero cursors
    prep<<<153, 256, 0, stream>>>(W1, W2, W3, WT1, WT2, WT3, cursor);
    // D2: layer-1 GEMM (unscaled) ∪ slab scatter
    gemm1_hist<<<GG + SB, 256, 0, stream>>>(x, WT1, bufG, n, srcI, dstI, cursor, packA, e);
    // D3: per-bucket sort -> CSR + row_ptr/deg/dinv
    buildB<<<NB, 256, 0, stream>>>(packA, cursor, row_ptr, deg, dinv, csr_src, n);
    // D4: aggregate layer 1 (uint2 gather, per-edge dinv)
    agg128_l1<<<(n + 3) / 4, 256, 0, stream>>>(bufG, row_ptr, deg, csr_src, dinv, b1, bufA, n);
    // D5: layer-2 GEMM (pre-scaled)
    gemm128_mfma<<<GG, 256, 0, stream>>>(bufA, WT2, dinv, bufG, n);
    // D6: aggregate layer 2 (uint2 gather)
    agg128<<<(n + 3) / 4, 256, 0, stream>>>(bufG, row_ptr, deg, csr_src, dinv, b2, bufA, n);
    // D7: layer-3 GEMM (40-wide, pre-scaled)
    gemm40_mfma<<<GG, 256, 0, stream>>>(bufA, WT3, dinv, bufG, n);
    // D8: aggregate + log_softmax -> out
    agg40_lsm<<<(n + 3) / 4, 256, 0, stream>>>(bufG, row_ptr, deg, csr_src, dinv, b3, out, n);
}